// Round 1
// 2266.968 us; speedup vs baseline: 1.0652x; 1.0652x over previous
//
#include <hip/hip_runtime.h>
#include <hip/hip_bf16.h>
#include <math.h>

typedef unsigned short u16;
typedef unsigned int u32;
typedef __attribute__((ext_vector_type(8))) short bf16x8_t;
typedef __attribute__((ext_vector_type(4))) float f32x4_t;

constexpr int SEQ = 1024;
constexpr int EMB = 768;
constexpr int PDIM = 128;
constexpr int NH = 16;
constexpr int HDIM = 48;
constexpr int DMLP = 3072;
constexpr int NFREQ = 256;

__device__ __forceinline__ float bf2f(u16 h) {
  union { u32 u; float f; } v; v.u = ((u32)h) << 16; return v.f;
}
__device__ __forceinline__ u16 f2bf(float f) {
  union { float f; u32 u; } v; v.f = f;
  u32 r = v.u + 0x7fffu + ((v.u >> 16) & 1u);
  return (u16)(r >> 16);
}
__device__ __forceinline__ u32 pack_bf2(float lo, float hi) {
  return (u32)f2bf(lo) | ((u32)f2bf(hi) << 16);
}
__device__ __forceinline__ float silu_f(float x) { return x / (1.f + expf(-x)); }
__device__ __forceinline__ float gelu_t(float x) {
  float x3 = x * x * x;
  return 0.5f * x * (1.f + tanhf(0.7978845608028654f * (x + 0.044715f * x3)));
}

// async global->LDS, 16B per lane. LDS dest must be wave-uniform base + lane*16.
__device__ __forceinline__ void gload16(const u16* g, u16* l) {
  __builtin_amdgcn_global_load_lds(
      (__attribute__((address_space(1))) void*)(void*)g,
      (__attribute__((address_space(3))) void*)l, 16, 0, 0);
}

// ---------------- time embedding ----------------
__global__ __launch_bounds__(256) void time1_kernel(
    const float* __restrict__ t, const float* __restrict__ t0_w,
    const float* __restrict__ t0_b, float* __restrict__ c1) {
  int e = (blockIdx.x * 256 + threadIdx.x) >> 6;
  int lane = threadIdx.x & 63;
  float tv = t[0];
  float acc = 0.f;
#pragma unroll
  for (int j = 0; j < 4; j++) {
    int i = lane + j * 64;
    int ii = (i < 128) ? i : (i - 128);
    float fr = expf(-9.210340371976184f * (float)ii / 128.f);
    float a = tv * fr;
    float ev = (i < 128) ? cosf(a) : sinf(a);
    acc += ev * t0_w[(long)e * NFREQ + i];
  }
#pragma unroll
  for (int m = 1; m < 64; m <<= 1) acc += __shfl_xor(acc, m, 64);
  if (lane == 0) {
    float s = acc + t0_b[e];
    c1[e] = silu_f(s);
  }
}

__global__ __launch_bounds__(256) void time2_kernel(
    const float* __restrict__ c1, const float* __restrict__ t2_w,
    const float* __restrict__ t2_b, float* __restrict__ cs) {
  int e = (blockIdx.x * 256 + threadIdx.x) >> 6;
  int lane = threadIdx.x & 63;
  float acc = 0.f;
#pragma unroll
  for (int j = 0; j < 12; j++)
    acc += c1[lane + j * 64] * t2_w[(long)e * EMB + lane + j * 64];
#pragma unroll
  for (int m = 1; m < 64; m <<= 1) acc += __shfl_xor(acc, m, 64);
  if (lane == 0) {
    float s = acc + t2_b[e];
    cs[e] = silu_f(s);
  }
}

// ---------------- ada vectors ----------------
__global__ __launch_bounds__(256) void ada_kernel(
    const float* __restrict__ cs,
    const float* __restrict__ blk_w, const float* __restrict__ blk_b,
    const float* __restrict__ fin_w, const float* __restrict__ fin_b,
    float* __restrict__ adas) {
  int r = (blockIdx.x * 256 + threadIdx.x) >> 6;
  int lane = threadIdx.x & 63;
  const float* wr = (r < 36864) ? (blk_w + (long)r * EMB)
                                : (fin_w + (long)(r - 36864) * EMB);
  float acc = 0.f;
#pragma unroll
  for (int j = 0; j < 12; j++)
    acc += cs[lane + j * 64] * wr[lane + j * 64];
#pragma unroll
  for (int m = 1; m < 64; m <<= 1) acc += __shfl_xor(acc, m, 64);
  if (lane == 0) {
    float b = (r < 36864) ? blk_b[r] : fin_b[r - 36864];
    adas[r] = acc + b;
  }
}

// ---------------- bias -> bh via MFMA ----------------
__global__ __launch_bounds__(256) void bias_bh_kernel(
    const float* __restrict__ bias, const float* __restrict__ gam,
    const float* __restrict__ bet, const float* __restrict__ w,
    u16* __restrict__ bh) {
  const int lane = threadIdx.x & 63;
  const int fm = lane & 15;
  const int fq = lane >> 4;

  bf16x8_t bfrag[4];
  float S = 0.f, T = 0.f;
#pragma unroll
  for (int t = 0; t < 4; t++) {
    int k0 = t * 32 + fq * 8;
    float4 w0 = *(const float4*)(w + fm * PDIM + k0);
    float4 w1 = *(const float4*)(w + fm * PDIM + k0 + 4);
    float4 g0 = *(const float4*)(gam + k0);
    float4 g1 = *(const float4*)(gam + k0 + 4);
    float4 e0 = *(const float4*)(bet + k0);
    float4 e1 = *(const float4*)(bet + k0 + 4);
    float wg[8] = {w0.x * g0.x, w0.y * g0.y, w0.z * g0.z, w0.w * g0.w,
                   w1.x * g1.x, w1.y * g1.y, w1.z * g1.z, w1.w * g1.w};
    S += wg[0] + wg[1] + wg[2] + wg[3] + wg[4] + wg[5] + wg[6] + wg[7];
    T += w0.x * e0.x + w0.y * e0.y + w0.z * e0.z + w0.w * e0.w +
         w1.x * e1.x + w1.y * e1.y + w1.z * e1.z + w1.w * e1.w;
    union { bf16x8_t f; u32 u[4]; } bu;
#pragma unroll
    for (int i = 0; i < 4; i++) bu.u[i] = pack_bf2(wg[2 * i], wg[2 * i + 1]);
    bfrag[t] = bu.f;
  }
  S += __shfl_xor(S, 16, 64); S += __shfl_xor(S, 32, 64);
  T += __shfl_xor(T, 16, 64); T += __shfl_xor(T, 32, 64);

  const long ngroup = (long)SEQ * SEQ / 16;
  const long nwave = (long)gridDim.x * 4;
  long gw = ((long)blockIdx.x * 256 + threadIdx.x) >> 6;
  for (long grp = gw; grp < ngroup; grp += nwave) {
    const float* bp = bias + grp * (16 * PDIM) + (long)fm * PDIM;
    float v[32];
#pragma unroll
    for (int t = 0; t < 4; t++) {
      float4 a0 = *(const float4*)(bp + t * 32 + fq * 8);
      float4 a1 = *(const float4*)(bp + t * 32 + fq * 8 + 4);
      v[t * 8 + 0] = a0.x; v[t * 8 + 1] = a0.y; v[t * 8 + 2] = a0.z; v[t * 8 + 3] = a0.w;
      v[t * 8 + 4] = a1.x; v[t * 8 + 5] = a1.y; v[t * 8 + 6] = a1.z; v[t * 8 + 7] = a1.w;
    }
    float s = 0.f, ss = 0.f;
#pragma unroll
    for (int i = 0; i < 32; i++) { s += v[i]; ss += v[i] * v[i]; }
    s += __shfl_xor(s, 16, 64); s += __shfl_xor(s, 32, 64);
    ss += __shfl_xor(ss, 16, 64); ss += __shfl_xor(ss, 32, 64);

    f32x4_t acc = {};
#pragma unroll
    for (int t = 0; t < 4; t++) {
      union { bf16x8_t f; u32 u[4]; } au;
#pragma unroll
      for (int i = 0; i < 4; i++)
        au.u[i] = pack_bf2(v[t * 8 + 2 * i], v[t * 8 + 2 * i + 1]);
      acc = __builtin_amdgcn_mfma_f32_16x16x32_bf16(au.f, bfrag[t], acc, 0, 0, 0);
    }
    long pbase = grp * 16;
#pragma unroll
    for (int r = 0; r < 4; r++) {
      int p = fq * 4 + r;
      float sp = __shfl(s, p, 64);
      float ssp = __shfl(ss, p, 64);
      float mu = sp * (1.f / PDIM);
      float rr = rsqrtf(ssp * (1.f / PDIM) - mu * mu + 1e-6f);
      float out = rr * (acc[r] - mu * S) + T;
      bh[(long)fm * SEQ * SEQ + pbase + p] = f2bf(out);
    }
  }
}

// ---------------- fp32 -> bf16 weight conversion (4 segments) ----------------
__global__ __launch_bounds__(256) void cvt4_kernel(
    const float* __restrict__ s0, int n0, const float* __restrict__ s1, int n1,
    const float* __restrict__ s2, int n2, const float* __restrict__ s3, int n3,
    u16* __restrict__ dst) {
  long total = ((long)n0 + n1 + n2 + n3) >> 2;
  for (long i = (long)blockIdx.x * 256 + threadIdx.x; i < total;
       i += (long)gridDim.x * 256) {
    long e = i << 2;
    const float* s; long off;
    if (e < n0) { s = s0; off = e; }
    else if (e < (long)n0 + n1) { s = s1; off = e - n0; }
    else if (e < (long)n0 + n1 + n2) { s = s2; off = e - n0 - n1; }
    else { s = s3; off = e - n0 - n1 - n2; }
    float4 v = *(const float4*)(s + off);
    ushort4 o;
    o.x = f2bf(v.x); o.y = f2bf(v.y); o.z = f2bf(v.z); o.w = f2bf(v.w);
    *(ushort4*)(dst + e) = o;
  }
}

// ---------------- LN + adaLN modulation -> bf16 ----------------
__global__ __launch_bounds__(256) void ln_mod_kernel(
    const float* __restrict__ x, const float* __restrict__ sh,
    const float* __restrict__ sc, u16* __restrict__ out) {
  int row = blockIdx.x * 4 + (threadIdx.x >> 6);
  int lane = threadIdx.x & 63;
  const float* xr = x + (long)row * EMB;
  float4 xv[3];
  float s = 0.f, ss = 0.f;
#pragma unroll
  for (int j = 0; j < 3; j++) {
    xv[j] = *(const float4*)(xr + j * 256 + lane * 4);
    s += xv[j].x + xv[j].y + xv[j].z + xv[j].w;
    ss += xv[j].x * xv[j].x + xv[j].y * xv[j].y + xv[j].z * xv[j].z + xv[j].w * xv[j].w;
  }
#pragma unroll
  for (int m = 1; m < 64; m <<= 1) {
    s += __shfl_xor(s, m, 64);
    ss += __shfl_xor(ss, m, 64);
  }
  float mu = s * (1.f / EMB);
  float r = rsqrtf(ss * (1.f / EMB) - mu * mu + 1e-6f);
#pragma unroll
  for (int j = 0; j < 3; j++) {
    int c = j * 256 + lane * 4;
    float4 shv = *(const float4*)(sh + c);
    float4 scv = *(const float4*)(sc + c);
    ushort4 o;
    o.x = f2bf((xv[j].x - mu) * r * (1.f + scv.x) + shv.x);
    o.y = f2bf((xv[j].y - mu) * r * (1.f + scv.y) + shv.y);
    o.z = f2bf((xv[j].z - mu) * r * (1.f + scv.z) + shv.z);
    o.w = f2bf((xv[j].w - mu) * r * (1.f + scv.w) + shv.w);
    *(ushort4*)(out + (long)row * EMB + c) = o;
  }
}

// ---------------- softmax (in-place, bf16, row length 1024) ----------------
__global__ __launch_bounds__(256) void softmax_kernel(u16* __restrict__ sp) {
  long row = (long)blockIdx.x * 4 + (threadIdx.x >> 6);
  int lane = threadIdx.x & 63;
  u16* p = sp + row * SEQ;
  uint4 u0 = *(uint4*)(p + lane * 8);
  uint4 u1 = *(uint4*)(p + 512 + lane * 8);
  float v[16];
  u32 uu[8] = {u0.x, u0.y, u0.z, u0.w, u1.x, u1.y, u1.z, u1.w};
#pragma unroll
  for (int i = 0; i < 8; i++) {
    v[2 * i] = bf2f((u16)(uu[i] & 0xffffu));
    v[2 * i + 1] = bf2f((u16)(uu[i] >> 16));
  }
  float mx = v[0];
#pragma unroll
  for (int i = 1; i < 16; i++) mx = fmaxf(mx, v[i]);
#pragma unroll
  for (int m = 1; m < 64; m <<= 1) mx = fmaxf(mx, __shfl_xor(mx, m, 64));
  float sum = 0.f;
#pragma unroll
  for (int i = 0; i < 16; i++) {
    v[i] = expf(v[i] - mx);
    sum += v[i];
  }
#pragma unroll
  for (int m = 1; m < 64; m <<= 1) sum += __shfl_xor(sum, m, 64);
  float inv = 1.f / sum;
#pragma unroll
  for (int i = 0; i < 8; i++)
    uu[i] = (u32)f2bf(v[2 * i] * inv) | ((u32)f2bf(v[2 * i + 1] * inv) << 16);
  *(uint4*)(p + lane * 8) = make_uint4(uu[0], uu[1], uu[2], uu[3]);
  *(uint4*)(p + 512 + lane * 8) = make_uint4(uu[4], uu[5], uu[6], uu[7]);
}

// ---------------- legacy 64x64 bf16 GEMM (attention logits / PV) ----------------
enum { M_PLAIN, M_QKV, M_LOGITS, M_PV, M_RESID, M_GELU };

template <int MODE>
__global__ __launch_bounds__(256) void gemm_bt_kernel(
    const u16* __restrict__ A, long sAz, int lda,
    const u16* __restrict__ Bt, long sBz, int ldb,
    int M, int N, int K,
    const float* __restrict__ bias, const float* __restrict__ gate,
    const u16* __restrict__ addb,
    float* __restrict__ outf, int ldo,
    u16* __restrict__ outb, long sObz, int ldob,
    u16* __restrict__ qout, u16* __restrict__ kout, u16* __restrict__ vtout,
    float qscale) {
  __shared__ __align__(16) u16 As[64][40];
  __shared__ __align__(16) u16 Bs[64][40];
  const int tid = threadIdx.x;
  const int lane = tid & 63, wid = tid >> 6;
  const int bm = blockIdx.y * 64, bn = blockIdx.x * 64;
  const int z = blockIdx.z;
  const u16* Ab = A + (long)z * sAz;
  const u16* Bb = Bt + (long)z * sBz;
  const int ar = tid >> 2, ac = (tid & 3) * 8;
  const int wm = (wid >> 1) * 32, wn = (wid & 1) * 32;
  const int fm = lane & 15, fq = lane >> 4;
  f32x4_t acc[2][2] = {};
  for (int k0 = 0; k0 < K; k0 += 32) {
    uint4 av = make_uint4(0, 0, 0, 0);
    if (k0 + ac < K)
      av = *(const uint4*)(Ab + (long)(bm + ar) * lda + (k0 + ac));
    *(uint4*)(&As[ar][ac]) = av;
    uint4 bv = make_uint4(0, 0, 0, 0);
    if ((bn + ar) < N && (k0 + ac) < K)
      bv = *(const uint4*)(Bb + (long)(bn + ar) * ldb + (k0 + ac));
    *(uint4*)(&Bs[ar][ac]) = bv;
    __syncthreads();
    bf16x8_t a0 = *(const bf16x8_t*)(&As[wm + fm][fq * 8]);
    bf16x8_t a1 = *(const bf16x8_t*)(&As[wm + 16 + fm][fq * 8]);
    bf16x8_t b0 = *(const bf16x8_t*)(&Bs[wn + fm][fq * 8]);
    bf16x8_t b1 = *(const bf16x8_t*)(&Bs[wn + 16 + fm][fq * 8]);
    acc[0][0] = __builtin_amdgcn_mfma_f32_16x16x32_bf16(a0, b0, acc[0][0], 0, 0, 0);
    acc[0][1] = __builtin_amdgcn_mfma_f32_16x16x32_bf16(a0, b1, acc[0][1], 0, 0, 0);
    acc[1][0] = __builtin_amdgcn_mfma_f32_16x16x32_bf16(a1, b0, acc[1][0], 0, 0, 0);
    acc[1][1] = __builtin_amdgcn_mfma_f32_16x16x32_bf16(a1, b1, acc[1][1], 0, 0, 0);
    __syncthreads();
  }
#pragma unroll
  for (int mf = 0; mf < 2; mf++)
#pragma unroll
    for (int nf = 0; nf < 2; nf++) {
      int col = bn + wn + nf * 16 + fm;
      if (col >= N) continue;
#pragma unroll
      for (int r = 0; r < 4; r++) {
        int row = bm + wm + mf * 16 + fq * 4 + r;
        float v = acc[mf][nf][r];
        if constexpr (MODE == M_LOGITS) {
          long idx = (long)z * sObz + (long)row * ldob + col;
          outb[idx] = f2bf(v + bf2f(addb[idx]));
        } else if constexpr (MODE == M_PV) {
          outb[(long)row * ldob + z * HDIM + col] = f2bf(v);
        }
      }
    }
}

// ---------------- 128x128 MFMA GEMM (m97 structure): C = A(MxK) * Bt(NxK)^T --------
// grid = (N/128, M/128, SPLITK); K param = per-chunk length (mult of 32).
// G_RESID accumulates into fp32 outf via atomicAdd (split-K safe).
enum { G_PLAIN, G_QKV, G_RESID, G_GELU };

template <int MODE>
__global__ __launch_bounds__(256) void gemm128_kernel(
    const u16* __restrict__ A, int lda,
    const u16* __restrict__ Bt, int ldb, int K,
    const float* __restrict__ bias, const float* __restrict__ gate,
    float* __restrict__ outf, int ldo,
    u16* __restrict__ outb, int ldob,
    u16* __restrict__ qout, u16* __restrict__ kout, u16* __restrict__ vtout,
    float qscale) {
  __shared__ __align__(16) u16 smem[8192];  // As[128][32] | Bs[128][32], linear
  const int tid = threadIdx.x;
  const int lane = tid & 63, wid = tid >> 6;
  const int bm = blockIdx.y * 128, bn = blockIdx.x * 128;
  const long koff = (long)blockIdx.z * K;
  // staging: thread tid covers LDS bytes tid*16 of each 4KB quarter
  // (= wave-uniform base wid*1024 + lane*16, as global_load_lds requires)
  const int r0 = tid >> 2;          // 0..63
  const int ce = (tid & 3) * 8;     // bf16 col 0,8,16,24
  const u16* gA0 = A + (long)(bm + r0) * lda + koff + ce;
  const u16* gA1 = gA0 + (long)64 * lda;
  const u16* gB0 = Bt + (long)(bn + r0) * ldb + koff + ce;
  const u16* gB1 = gB0 + (long)64 * ldb;
  u16* lA0 = &smem[r0 * 32 + ce];
  u16* lA1 = lA0 + 64 * 32;
  u16* lB0 = lA0 + 4096;
  u16* lB1 = lB0 + 64 * 32;
  // compute: wave (wid) owns 64x64 at (wm, wn); 4x4 frags of 16x16
  const int wm = (wid >> 1) * 64, wn = (wid & 1) * 64;
  const int fm = lane & 15, fq = lane >> 4;
  const u16* pa = &smem[(wm + fm) * 32 + fq * 8];
  const u16* pb = &smem[4096 + (wn + fm) * 32 + fq * 8];
  f32x4_t acc[4][4] = {};
  for (int k0 = 0; k0 < K; k0 += 32) {
    gload16(gA0 + k0, lA0);
    gload16(gA1 + k0, lA1);
    gload16(gB0 + k0, lB0);
    gload16(gB1 + k0, lB1);
    __syncthreads();
    bf16x8_t a[4], b[4];
#pragma unroll
    for (int i = 0; i < 4; i++) a[i] = *(const bf16x8_t*)(pa + i * 16 * 32);
#pragma unroll
    for (int i = 0; i < 4; i++) b[i] = *(const bf16x8_t*)(pb + i * 16 * 32);
#pragma unroll
    for (int mf = 0; mf < 4; mf++)
#pragma unroll
      for (int nf = 0; nf < 4; nf++)
        acc[mf][nf] = __builtin_amdgcn_mfma_f32_16x16x32_bf16(a[mf], b[nf], acc[mf][nf], 0, 0, 0);
    __syncthreads();
  }
#pragma unroll
  for (int nf = 0; nf < 4; nf++) {
    const int col = bn + wn + nf * 16 + fm;
    int hh = 0, tt = 0, cc = 0;
    if constexpr (MODE == G_QKV) {
      hh = col / (3 * HDIM);
      int rr2 = col - hh * 3 * HDIM;
      tt = rr2 / HDIM;
      cc = rr2 - tt * HDIM;
    }
    float bcol = 0.f, gcol = 0.f;
    if constexpr (MODE == G_PLAIN || MODE == G_GELU) bcol = bias[col];
    if constexpr (MODE == G_RESID) {
      gcol = gate[col];
      bcol = (blockIdx.z == 0) ? bias[col] : 0.f;
    }
#pragma unroll
    for (int mf = 0; mf < 4; mf++) {
#pragma unroll
      for (int r = 0; r < 4; r++) {
        const int row = bm + wm + mf * 16 + fq * 4 + r;
        float v = acc[mf][nf][r];
        if constexpr (MODE == G_PLAIN) {
          outf[(long)row * ldo + col] = v + bcol;
        } else if constexpr (MODE == G_QKV) {
          if (tt == 0)
            qout[(long)hh * SEQ * HDIM + (long)row * HDIM + cc] = f2bf(v * qscale);
          else if (tt == 1)
            kout[(long)hh * SEQ * HDIM + (long)row * HDIM + cc] = f2bf(v);
          else
            vtout[(long)hh * HDIM * SEQ + (long)cc * SEQ + row] = f2bf(v);
        } else if constexpr (MODE == G_RESID) {
          atomicAdd(&outf[(long)row * ldo + col], gcol * (v + bcol));
        } else if constexpr (MODE == G_GELU) {
          outb[(long)row * ldob + col] = f2bf(gelu_t(v + bcol));
        }
      }
    }
  }
}

// ---------------- host ----------------
extern "C" void kernel_launch(void* const* d_in, const int* in_sizes, int n_in,
                              void* d_out, int out_size, void* d_ws, size_t ws_size,
                              hipStream_t stream) {
  const float* z = (const float*)d_in[0];
  const float* t = (const float*)d_in[1];
  const float* bias = (const float*)d_in[2];
  const float* p2s_ln_g = (const float*)d_in[3];
  const float* p2s_ln_b = (const float*)d_in[4];
  const float* p2s_w = (const float*)d_in[5];
  const float* t0_w = (const float*)d_in[6];
  const float* t0_b = (const float*)d_in[7];
  const float* t2_w = (const float*)d_in[8];
  const float* t2_b = (const float*)d_in[9];
  const float* blk_proj_w = (const float*)d_in[10];
  const float* blk_o_w = (const float*)d_in[11];
  const float* blk_o_b = (const float*)d_in[12];
  const float* blk_ada_w = (const float*)d_in[13];
  const float* blk_ada_b = (const float*)d_in[14];
  const float* blk_fc1_w = (const float*)d_in[15];
  const float* blk_fc1_b = (const float*)d_in[16];
  const float* blk_fc2_w = (const float*)d_in[17];
  const float* blk_fc2_b = (const float*)d_in[18];
  const float* fin_ada_w = (const float*)d_in[19];
  const float* fin_ada_b = (const float*)d_in[20];
  const float* fin_w = (const float*)d_in[21];
  const float* fin_b = (const float*)d_in[22];

  char* base = (char*)d_ws;
  size_t off = 0;
  auto alloc = [&](size_t bytes) {
    void* p = base + off;
    off += (bytes + 255) & ~(size_t)255;
    return p;
  };
  float* x = (float*)alloc((size_t)SEQ * EMB * 4);
  float* c1 = (float*)alloc(EMB * 4);
  float* cs = (float*)alloc(EMB * 4);
  float* adas = (float*)alloc(38400 * 4);
  u16* hbuf = (u16*)alloc((size_t)SEQ * EMB * 2);
  u16* qb = (u16*)alloc((size_t)NH * SEQ * HDIM * 2);
  u16* kb = (u16*)alloc((size_t)NH * SEQ * HDIM * 2);
  u16* vtb = (u16*)alloc((size_t)NH * SEQ * HDIM * 2);
  u16* y2 = (u16*)alloc((size_t)SEQ * EMB * 2);
  u16* mlp = (u16*)alloc((size_t)SEQ * DMLP * 2);
  u16* bh = (u16*)alloc((size_t)NH * SEQ * SEQ * 2);
  u16* SP = (u16*)alloc((size_t)NH * SEQ * SEQ * 2);
  u16* wball = (u16*)alloc((size_t)56623104 * 2);  // all 8 layers bf16
  u16* wfin = (u16*)alloc((size_t)589824 * 2);
  (void)ws_size; (void)in_sizes; (void)n_in; (void)out_size;

  hipMemcpyAsync(x, z, (size_t)SEQ * EMB * 4, hipMemcpyDeviceToDevice, stream);
  time1_kernel<<<192, 256, 0, stream>>>(t, t0_w, t0_b, c1);
  time2_kernel<<<192, 256, 0, stream>>>(c1, t2_w, t2_b, cs);
  ada_kernel<<<9600, 256, 0, stream>>>(cs, blk_ada_w, blk_ada_b, fin_ada_w, fin_ada_b, adas);
  bias_bh_kernel<<<1024, 256, 0, stream>>>(bias, p2s_ln_g, p2s_ln_b, p2s_w, bh);
  // convert ALL block weights once (4 contiguous stacked tensors), plus final proj
  cvt4_kernel<<<2048, 256, 0, stream>>>(blk_proj_w, 14155776, blk_o_w, 4718592,
                                        blk_fc1_w, 18874368, blk_fc2_w, 18874368, wball);
  cvt4_kernel<<<576, 256, 0, stream>>>(fin_w, 589824, nullptr, 0, nullptr, 0, nullptr, 0, wfin);

  const float qscale = 1.0f / sqrtf((float)HDIM);
  const long o_base = 14155776;
  const long f1_base = 18874368;
  const long f2_base = 37748736;

  for (int d = 0; d < 8; d++) {
    const u16* pw = wball + (long)d * 2304 * 768;
    const u16* ow = wball + o_base + (long)d * 768 * 768;
    const u16* f1 = wball + f1_base + (long)d * 3072 * 768;
    const u16* f2 = wball + f2_base + (long)d * 768 * 3072;
    const float* ada = adas + d * 4608;

    ln_mod_kernel<<<256, 256, 0, stream>>>(x, ada + 0, ada + 768, hbuf);
    gemm128_kernel<G_QKV><<<dim3(18, 8, 1), 256, 0, stream>>>(
        hbuf, EMB, pw, EMB, EMB,
        nullptr, nullptr, nullptr, 0, nullptr, 0,
        qb, kb, vtb, qscale);
    gemm_bt_kernel<M_LOGITS><<<dim3(16, 16, 16), 256, 0, stream>>>(
        qb, (long)SEQ * HDIM, HDIM, kb, (long)SEQ * HDIM, HDIM, SEQ, SEQ, HDIM,
        nullptr, nullptr, bh, nullptr, 0, SP, (long)SEQ * SEQ, SEQ,
        nullptr, nullptr, nullptr, 0.f);
    softmax_kernel<<<4096, 256, 0, stream>>>(SP);
    gemm_bt_kernel<M_PV><<<dim3(1, 16, 16), 256, 0, stream>>>(
        SP, (long)SEQ * SEQ, SEQ, vtb, (long)HDIM * SEQ, SEQ, SEQ, HDIM, SEQ,
        nullptr, nullptr, nullptr, nullptr, 0, y2, 0, EMB,
        nullptr, nullptr, nullptr, 0.f);
    // O-proj: K=768 split 4x192, atomic accumulate into x
    gemm128_kernel<G_RESID><<<dim3(6, 8, 4), 256, 0, stream>>>(
        y2, EMB, ow, EMB, 192,
        blk_o_b + d * EMB, ada + 1536, x, EMB, nullptr, 0,
        nullptr, nullptr, nullptr, 0.f);
    ln_mod_kernel<<<256, 256, 0, stream>>>(x, ada + 2304, ada + 3072, hbuf);
    gemm128_kernel<G_GELU><<<dim3(24, 8, 1), 256, 0, stream>>>(
        hbuf, EMB, f1, EMB, EMB,
        blk_fc1_b + d * DMLP, nullptr, nullptr, 0, mlp, DMLP,
        nullptr, nullptr, nullptr, 0.f);
    // FC2: K=3072 split 4x768, atomic accumulate into x
    gemm128_kernel<G_RESID><<<dim3(6, 8, 4), 256, 0, stream>>>(
        mlp, DMLP, f2, DMLP, 768,
        blk_fc2_b + d * EMB, ada + 3840, x, EMB, nullptr, 0,
        nullptr, nullptr, nullptr, 0.f);
  }
  ln_mod_kernel<<<256, 256, 0, stream>>>(x, adas + 36864, adas + 36864 + 768, hbuf);
  gemm128_kernel<G_PLAIN><<<dim3(6, 8, 1), 256, 0, stream>>>(
      hbuf, EMB, wfin, EMB, EMB,
      fin_b, nullptr, (float*)d_out, EMB, nullptr, 0,
      nullptr, nullptr, nullptr, 0.f);
}